// Round 1
// 10486.322 us; speedup vs baseline: 1.0724x; 1.0724x over previous
//
#include <hip/hip_runtime.h>
#include <math.h>

#define NEGF   (-1e30f)
#define FINTH  (-5e29f)
#define VSZ    32000
#define KBM    5
#define BB     32
#define SEQL   34   // T+1 where T = 33

__device__ __forceinline__ bool cand_gt(float av, int ai, float bv, int bi) {
  return (av > bv) || (av == bv && ai < bi);
}

// top-5 insertion, maintains (tv0..tv4, ti0..ti4) sorted desc by (val, -idx)
#define INS5(xx, ii)                                                           \
  if (cand_gt(xx, ii, tv4, ti4)) {                                             \
    tv4 = xx; ti4 = ii;                                                        \
    if (cand_gt(tv4, ti4, tv3, ti3)) { float tf = tv3; int tj = ti3; tv3 = tv4; ti3 = ti4; tv4 = tf; ti4 = tj; \
      if (cand_gt(tv3, ti3, tv2, ti2)) { tf = tv2; tj = ti2; tv2 = tv3; ti2 = ti3; tv3 = tf; ti3 = tj; \
        if (cand_gt(tv2, ti2, tv1, ti1)) { tf = tv1; tj = ti1; tv1 = tv2; ti1 = ti2; tv2 = tf; ti2 = tj; \
          if (cand_gt(tv1, ti1, tv0, ti0)) { tf = tv0; tj = ti0; tv0 = tv1; ti0 = ti1; tv1 = tf; ti1 = tj; } } } } }

// ---------------- init ----------------
__global__ void init_kernel(float* hb0, int* word_buf, int* hsrc) {
  int i = blockIdx.x * 256 + threadIdx.x;
  if (i < 32 * 512) hb0[i] = 0.f;
  if (i < 160) { word_buf[i] = 0; hsrc[i] = i / KBM; }
}

// ---------------- gates GEMM: gi = x@Wih^T + bih, gh = h@Whh^T + bhh ----------------
// Direct-global register-tiled: no LDS, no barriers.
// 256 threads: ng = tid&7 (8 groups x 2 j), mg = tid>>3 (32 groups x P rows).
// W is [j][k] (k-contiguous) -> float4 over k for both operands.
// grid.x = 1536/16 = 96, grid.y = 0: gi, 1: gh.  M = 32*P.
template<int P>
__global__ __launch_bounds__(256) void gates_kernel(
    const float* __restrict__ emb, const int* __restrict__ tok_ptr, int tok_stride,
    const float* __restrict__ hbuf, const int* __restrict__ hsrc,
    const float* __restrict__ Wih, const float* __restrict__ Whh,
    const float* __restrict__ bih, const float* __restrict__ bhh,
    float* __restrict__ gi, float* __restrict__ gh)
{
  const bool is_h = (blockIdx.y != 0);
  const float* W    = is_h ? Whh : Wih;
  const float* bias = is_h ? bhh : bih;
  float* out        = is_h ? gh  : gi;

  const int tid = threadIdx.x;
  const int ng = tid & 7;
  const int mg = tid >> 3;
  const int j0 = blockIdx.x * 16 + ng * 2;

  const float* arow[P];
  #pragma unroll
  for (int i = 0; i < P; i++) {
    int m = mg * P + i;
    if (is_h) { int r = hsrc ? hsrc[m] : m; arow[i] = hbuf + (long)r * 512; }
    else      { int tk = tok_ptr[m * tok_stride]; arow[i] = emb + (long)tk * 512; }
  }
  const float* w0p = W + (long)j0 * 512;
  const float* w1p = w0p + 512;

  float acc0[P], acc1[P];
  #pragma unroll
  for (int i = 0; i < P; i++) { acc0[i] = 0.f; acc1[i] = 0.f; }

  #pragma unroll 2
  for (int k = 0; k < 512; k += 4) {
    float4 w0 = *(const float4*)(w0p + k);
    float4 w1 = *(const float4*)(w1p + k);
    #pragma unroll
    for (int i = 0; i < P; i++) {
      float4 a = *(const float4*)(arow[i] + k);
      acc0[i] += a.x * w0.x + a.y * w0.y + a.z * w0.z + a.w * w0.w;
      acc1[i] += a.x * w1.x + a.y * w1.y + a.z * w1.z + a.w * w1.w;
    }
  }
  float b0 = bias[j0], b1 = bias[j0 + 1];
  #pragma unroll
  for (int i = 0; i < P; i++) {
    int m = mg * P + i;
    float2 r; r.x = acc0[i] + b0; r.y = acc1[i] + b1;
    *(float2*)(out + (long)m * 1536 + j0) = r;
  }
}

// ---------------- GRU elementwise update ----------------
__global__ __launch_bounds__(256) void hupd_kernel(
    const float* __restrict__ gi, const float* __restrict__ gh,
    const float* __restrict__ hin, const int* __restrict__ hsrc,
    float* __restrict__ hout, int M)
{
  int idx = blockIdx.x * 256 + threadIdx.x;
  if (idx >= M * 512) return;
  int m = idx >> 9, i = idx & 511;
  const float* gim = gi + (long)m * 1536;
  const float* ghm = gh + (long)m * 1536;
  float ir = gim[i], iz = gim[512 + i], inn = gim[1024 + i];
  float hr = ghm[i], hz = ghm[512 + i], hn = ghm[1024 + i];
  float r = 1.f / (1.f + expf(-(ir + hr)));
  float z = 1.f / (1.f + expf(-(iz + hz)));
  float n = tanhf(inn + r * hn);
  int src = hsrc ? hsrc[m] : m;
  float h = hin[(long)src * 512 + i];
  hout[(long)m * 512 + i] = (1.f - z) * n + z * h;
}

// ---------------- logits GEMM: logits = h1 @ W_out + b_out (160 x 32000, K=512) ----
// LDS-free register-tiled GEMM. 256 threads: ng = tid&7 (8 groups x 8 v),
// mg = tid>>3 (32 groups x 5 m). Block covers all 160 m x 64 v; grid = 500.
// A reads: 8-lane broadcast (same addr). W reads: coalesced 256B span per wave.
// Per 4-k chunk: 13 dwordx4 loads feed 160 FMAs -> VALU-bound.
__global__ __launch_bounds__(256, 2) void logits_kernel(
    const float* __restrict__ h1, const float* __restrict__ Wout,
    const float* __restrict__ bout, float* __restrict__ logits)
{
  const int tid = threadIdx.x;
  const int ng = tid & 7;
  const int mg = tid >> 3;
  const int v  = blockIdx.x * 64 + ng * 8;
  const int m0 = mg * 5;

  const float* a0 = h1 + (long)m0 * 512;
  const float* wk = Wout + v;

  float4 acc[5][2];
  #pragma unroll
  for (int i = 0; i < 5; i++) {
    acc[i][0] = make_float4(0.f, 0.f, 0.f, 0.f);
    acc[i][1] = make_float4(0.f, 0.f, 0.f, 0.f);
  }

  for (int k = 0; k < 512; k += 4) {
    float4 a[5];
    #pragma unroll
    for (int i = 0; i < 5; i++) a[i] = *(const float4*)(a0 + i * 512 + k);
#define KSTEP(COMP)                                                   \
    {                                                                 \
      float4 w0 = *(const float4*)wk;                                 \
      float4 w1 = *(const float4*)(wk + 4);                           \
      wk += VSZ;                                                      \
      _Pragma("unroll")                                               \
      for (int i = 0; i < 5; i++) {                                   \
        float s = a[i].COMP;                                          \
        acc[i][0].x += s * w0.x; acc[i][0].y += s * w0.y;             \
        acc[i][0].z += s * w0.z; acc[i][0].w += s * w0.w;             \
        acc[i][1].x += s * w1.x; acc[i][1].y += s * w1.y;             \
        acc[i][1].z += s * w1.z; acc[i][1].w += s * w1.w;             \
      }                                                               \
    }
    KSTEP(x) KSTEP(y) KSTEP(z) KSTEP(w)
#undef KSTEP
  }
  float4 b0 = *(const float4*)(bout + v);
  float4 b1 = *(const float4*)(bout + v + 4);
  #pragma unroll
  for (int i = 0; i < 5; i++) {
    float4 r0, r1;
    r0.x = acc[i][0].x + b0.x; r0.y = acc[i][0].y + b0.y;
    r0.z = acc[i][0].z + b0.z; r0.w = acc[i][0].w + b0.w;
    r1.x = acc[i][1].x + b1.x; r1.y = acc[i][1].y + b1.y;
    r1.z = acc[i][1].z + b1.z; r1.w = acc[i][1].w + b1.w;
    *(float4*)(logits + (long)(m0 + i) * VSZ + v)     = r0;
    *(float4*)(logits + (long)(m0 + i) * VSZ + v + 4) = r1;
  }
}

// ---------------- fused per-row logsumexp + top-5 (single pass over logits) ------
// Within a row, candidate value a + (logit - lse) is monotone in logit, so the
// global top-5 over K rows is a subset of the union of per-row top-5s.
__global__ __launch_bounds__(256) void rowtop_kernel(
    const float* __restrict__ logits, float* __restrict__ lse,
    float* __restrict__ rv5, int* __restrict__ ri5)
{
  int row = blockIdx.x, tid = threadIdx.x;
  const float4* x4 = (const float4*)(logits + (long)row * VSZ);
  float m = -3.4e38f, s = 0.f;
  float tv0 = -3.4e38f, tv1 = -3.4e38f, tv2 = -3.4e38f, tv3 = -3.4e38f, tv4 = -3.4e38f;
  int ti0 = 0x7fffffff, ti1 = 0x7fffffff, ti2 = 0x7fffffff, ti3 = 0x7fffffff, ti4 = 0x7fffffff;

  for (int i = tid; i < VSZ / 4; i += 256) {
    float4 c = x4[i];
    float vm = fmaxf(fmaxf(c.x, c.y), fmaxf(c.z, c.w));
    if (vm > m) { s *= expf(m - vm); m = vm; }
    s += expf(c.x - m) + expf(c.y - m) + expf(c.z - m) + expf(c.w - m);
    int id0 = i * 4;
    INS5(c.x, id0); INS5(c.y, id0 + 1); INS5(c.z, id0 + 2); INS5(c.w, id0 + 3);
  }
  // wave-level lse reduce
  for (int mask = 1; mask < 64; mask <<= 1) {
    float om = __shfl_xor(m, mask, 64);
    float os = __shfl_xor(s, mask, 64);
    float nm = fmaxf(m, om);
    s = s * expf(m - nm) + os * expf(om - nm);
    m = nm;
  }
  __shared__ float sm[4], ss[4];
  __shared__ float sv[256 * 5];
  __shared__ int   si[256 * 5];
  if ((tid & 63) == 0) { sm[tid >> 6] = m; ss[tid >> 6] = s; }
  sv[tid * 5 + 0] = tv0; si[tid * 5 + 0] = ti0;
  sv[tid * 5 + 1] = tv1; si[tid * 5 + 1] = ti1;
  sv[tid * 5 + 2] = tv2; si[tid * 5 + 2] = ti2;
  sv[tid * 5 + 3] = tv3; si[tid * 5 + 3] = ti3;
  sv[tid * 5 + 4] = tv4; si[tid * 5 + 4] = ti4;
  __syncthreads();
  if (tid == 0) {
    float M2 = sm[0], S2 = ss[0];
    for (int w = 1; w < 4; w++) {
      float nm = fmaxf(M2, sm[w]);
      S2 = S2 * expf(M2 - nm) + ss[w] * expf(sm[w] - nm);
      M2 = nm;
    }
    lse[row] = M2 + logf(S2);
  }
  for (int str = 128; str >= 1; str >>= 1) {
    if (tid < str) {
      float* av = &sv[tid * 5];         int* ai = &si[tid * 5];
      float* bv = &sv[(tid + str) * 5]; int* bi = &si[(tid + str) * 5];
      float o0[5]; int o1[5];
      int i = 0, j = 0;
      #pragma unroll
      for (int o = 0; o < 5; o++) {
        float avv = av[i]; int aii = ai[i];
        float bvv = bv[j]; int bii = bi[j];
        bool ta = cand_gt(avv, aii, bvv, bii);
        o0[o] = ta ? avv : bvv; o1[o] = ta ? aii : bii;
        i += ta ? 1 : 0; j += ta ? 0 : 1;
      }
      #pragma unroll
      for (int o = 0; o < 5; o++) { av[o] = o0[o]; ai[o] = o1[o]; }
    }
    __syncthreads();
  }
  if (tid == 0) {
    #pragma unroll
    for (int o = 0; o < 5; o++) { rv5[row * 5 + o] = sv[o]; ri5[row * 5 + o] = si[o]; }
  }
}

// ---------------- step-0 bookkeeping (kcount=1: row b*KBM only, a = 0) -----------
__global__ void book0_kernel(const float* __restrict__ rv5, const int* __restrict__ ri5,
                             const float* __restrict__ lse,
                             int* __restrict__ seqs, float* __restrict__ act_ll,
                             int* __restrict__ word_buf, int* __restrict__ hsrc,
                             float* __restrict__ best_ll, int* __restrict__ best_seq)
{
  int b = blockIdx.x, tid = threadIdx.x;
  int row = b * KBM;
  float l = lse[row];
  if (tid < SEQL) {
    for (int j = 0; j < KBM; j++) {
      int w = ri5[row * 5 + j];
      seqs[(b * KBM + j) * SEQL + tid] = (tid == 0) ? 0 : (tid == 1 ? w : 2);
    }
    best_seq[b * SEQL + tid] = 2;
  }
  if (tid < KBM) {
    act_ll[b * KBM + tid] = rv5[row * 5 + tid] - l;
    word_buf[b * KBM + tid] = ri5[row * 5 + tid];
    hsrc[b * KBM + tid] = b * KBM + tid;
  }
  if (tid == 0) best_ll[b] = NEGF;
}

// ---------------- per-step bookkeeping (25-candidate merge folded in) ------------
__global__ void book_kernel(const float* __restrict__ rv5, const int* __restrict__ ri5,
                            const float* __restrict__ lse,
                            const int* __restrict__ seqs_old, int* __restrict__ seqs_new,
                            float* __restrict__ act_ll, int* __restrict__ word_buf,
                            int* __restrict__ hsrc, float* __restrict__ best_ll,
                            int* __restrict__ best_seq, int t)
{
  int b = blockIdx.x, tid = threadIdx.x;
  __shared__ float sv5[5];
  __shared__ int   si5[5];
  if (tid == 0) {
    float tv0 = -3.4e38f, tv1 = -3.4e38f, tv2 = -3.4e38f, tv3 = -3.4e38f, tv4 = -3.4e38f;
    int ti0 = 0x7fffffff, ti1 = 0x7fffffff, ti2 = 0x7fffffff, ti3 = 0x7fffffff, ti4 = 0x7fffffff;
    for (int k = 0; k < KBM; k++) {
      int row = b * KBM + k;
      float a = act_ll[row], l = lse[row];
      #pragma unroll
      for (int j = 0; j < 5; j++) {
        float x = a + (rv5[row * 5 + j] - l);   // same rounding as full-scan version
        int id = k * VSZ + ri5[row * 5 + j];
        INS5(x, id);
      }
    }
    sv5[0] = tv0; si5[0] = ti0; sv5[1] = tv1; si5[1] = ti1;
    sv5[2] = tv2; si5[2] = ti2; sv5[3] = tv3; si5[3] = ti3;
    sv5[4] = tv4; si5[4] = ti4;
  }
  __syncthreads();

  __shared__ int ls[KBM][SEQL];
  float v[KBM]; int pr[KBM], wd[KBM];
  #pragma unroll
  for (int j = 0; j < KBM; j++) {
    v[j] = sv5[j];
    int id = si5[j];
    pr[j] = id / VSZ; wd[j] = id % VSZ;
  }
  #pragma unroll
  for (int j = 0; j < KBM; j++) {
    if (tid < SEQL) {
      int x = (tid == t + 1) ? wd[j] : seqs_old[(b * KBM + pr[j]) * SEQL + tid];
      ls[j][tid] = x;
      seqs_new[(b * KBM + j) * SEQL + tid] = x;
    }
  }
  __syncthreads();
  float cll[KBM];
  #pragma unroll
  for (int j = 0; j < KBM; j++) {
    bool fin = v[j] > FINTH;
    bool eos = (wd[j] == 1) && fin;
    cll[j] = eos ? v[j] / (float)(t + 2) : NEGF;
  }
  int jb = 0; float cb = cll[0];
  #pragma unroll
  for (int j = 1; j < KBM; j++) if (cll[j] > cb) { cb = cll[j]; jb = j; }
  bool improve = cb > best_ll[b];
  if (improve) {
    if (tid == 0) best_ll[b] = cb;
    if (tid < SEQL) best_seq[b * SEQL + tid] = ls[jb][tid];
  }
  if (tid < KBM) {
    int j = tid;
    bool fin = v[j] > FINTH;
    bool eos = (wd[j] == 1) && fin;
    act_ll[b * KBM + j] = (fin && !eos) ? v[j] : NEGF;
    word_buf[b * KBM + j] = wd[j];
    hsrc[b * KBM + j] = b * KBM + pr[j];
  }
}

// ---------------- winner selection ----------------
__global__ void final_kernel(const float* __restrict__ best_ll, const int* __restrict__ best_seq,
                             const float* __restrict__ act_ll, const int* __restrict__ seqs,
                             int* __restrict__ out)
{
  int b = blockIdx.x, tid = threadIdx.x;
  bool have = best_ll[b] > FINTH;
  int jb = 0; float ab = act_ll[b * KBM];
  for (int j = 1; j < KBM; j++)
    if (act_ll[b * KBM + j] > ab) { ab = act_ll[b * KBM + j]; jb = j; }
  if (tid < SEQL)
    out[b * SEQL + tid] = have ? best_seq[b * SEQL + tid]
                               : seqs[(b * KBM + jb) * SEQL + tid];
}

extern "C" void kernel_launch(void* const* d_in, const int* in_sizes, int n_in,
                              void* d_out, int out_size, void* d_ws, size_t ws_size,
                              hipStream_t stream)
{
  const int*   source  = (const int*)d_in[0];
  const float* emb_src = (const float*)d_in[1];
  const float* emb_tgt = (const float*)d_in[2];
  const float* eWih = (const float*)d_in[3];
  const float* eWhh = (const float*)d_in[4];
  const float* ebih = (const float*)d_in[5];
  const float* ebhh = (const float*)d_in[6];
  const float* dWih = (const float*)d_in[7];
  const float* dWhh = (const float*)d_in[8];
  const float* dbih = (const float*)d_in[9];
  const float* dbhh = (const float*)d_in[10];
  const float* Wout = (const float*)d_in[11];
  const float* bout = (const float*)d_in[12];
  int* out = (int*)d_out;

  char* ws = (char*)d_ws;
  size_t off = 0;
  auto alloc = [&](size_t bytes) {
    void* p = ws + off;
    off = (off + bytes + 255) & ~(size_t)255;
    return p;
  };
  float* hb0     = (float*)alloc(160 * 512 * 4);
  float* hb1     = (float*)alloc(160 * 512 * 4);
  float* gi      = (float*)alloc(160 * 1536 * 4);
  float* gh      = (float*)alloc(160 * 1536 * 4);
  float* logits  = (float*)alloc((size_t)160 * VSZ * 4);
  float* lse     = (float*)alloc(160 * 4);
  float* act_ll  = (float*)alloc(160 * 4);
  float* rv5     = (float*)alloc(160 * 5 * 4);
  float* best_ll = (float*)alloc(32 * 4);
  int*   ri5     = (int*)alloc(160 * 5 * 4);
  int*   seqs0   = (int*)alloc(160 * SEQL * 4);
  int*   seqs1   = (int*)alloc(160 * SEQL * 4);
  int*   wordb   = (int*)alloc(160 * 4);
  int*   hsrc    = (int*)alloc(160 * 4);
  int*   bseq    = (int*)alloc(32 * SEQL * 4);

  init_kernel<<<64, 256, 0, stream>>>(hb0, wordb, hsrc);

  // ---- encoder: 32 GRU steps over source tokens (M = 32) ----
  for (int s = 0; s < 32; s++) {
    gates_kernel<1><<<dim3(96, 2), 256, 0, stream>>>(
        emb_src, source + s, 32, hb0, nullptr,
        eWih, eWhh, ebih, ebhh, gi, gh);
    hupd_kernel<<<64, 256, 0, stream>>>(gi, gh, hb0, nullptr, hb0, 32);
  }

  // ---- decode step 0 (initial advance) ----
  gates_kernel<5><<<dim3(96, 2), 256, 0, stream>>>(
      emb_tgt, wordb, 1, hb0, hsrc, dWih, dWhh, dbih, dbhh, gi, gh);
  hupd_kernel<<<320, 256, 0, stream>>>(gi, gh, hb0, hsrc, hb1, 160);
  logits_kernel<<<500, 256, 0, stream>>>(hb1, Wout, bout, logits);
  rowtop_kernel<<<160, 256, 0, stream>>>(logits, lse, rv5, ri5);
  book0_kernel<<<32, 64, 0, stream>>>(rv5, ri5, lse, seqs0, act_ll, wordb, hsrc,
                                      best_ll, bseq);

  // ---- decode steps t = 1..32 ----
  float* hcur = hb1; float* hoth = hb0;
  int* scur = seqs0; int* soth = seqs1;
  for (int t = 1; t <= 32; t++) {
    gates_kernel<5><<<dim3(96, 2), 256, 0, stream>>>(
        emb_tgt, wordb, 1, hcur, hsrc, dWih, dWhh, dbih, dbhh, gi, gh);
    hupd_kernel<<<320, 256, 0, stream>>>(gi, gh, hcur, hsrc, hoth, 160);
    logits_kernel<<<500, 256, 0, stream>>>(hoth, Wout, bout, logits);
    rowtop_kernel<<<160, 256, 0, stream>>>(logits, lse, rv5, ri5);
    book_kernel<<<32, 64, 0, stream>>>(rv5, ri5, lse, scur, soth, act_ll, wordb,
                                       hsrc, best_ll, bseq, t);
    { float* tmp = hcur; hcur = hoth; hoth = tmp; }
    { int* tmp = scur; scur = soth; soth = tmp; }
  }

  final_kernel<<<32, 64, 0, stream>>>(best_ll, bseq, act_ll, scur, out);
}

// Round 2
// 8174.180 us; speedup vs baseline: 1.3757x; 1.2829x over previous
//
#include <hip/hip_runtime.h>
#include <math.h>

#define NEGF   (-1e30f)
#define FINTH  (-5e29f)
#define VSZ    32000
#define KBM    5
#define SEQL   34   // T+1 where T = 33
#define NVBLK  1000 // logtop blocks (32 v each)

__device__ __forceinline__ bool cand_gt(float av, int ai, float bv, int bi) {
  return (av > bv) || (av == bv && ai < bi);
}

// top-5 insertion, maintains (tv0..tv4, ti0..ti4) sorted desc by (val, -idx)
#define INS5(xx, ii)                                                           \
  if (cand_gt(xx, ii, tv4, ti4)) {                                             \
    tv4 = xx; ti4 = ii;                                                        \
    if (cand_gt(tv4, ti4, tv3, ti3)) { float tf = tv3; int tj = ti3; tv3 = tv4; ti3 = ti4; tv4 = tf; ti4 = tj; \
      if (cand_gt(tv3, ti3, tv2, ti2)) { tf = tv2; tj = ti2; tv2 = tv3; ti2 = ti3; tv3 = tf; ti3 = tj; \
        if (cand_gt(tv2, ti2, tv1, ti1)) { tf = tv1; tj = ti1; tv1 = tv2; ti1 = ti2; tv2 = tf; ti2 = tj; \
          if (cand_gt(tv1, ti1, tv0, ti0)) { tf = tv0; tj = ti0; tv0 = tv1; ti0 = ti1; tv1 = tf; ti1 = tj; } } } } }

// ---------------- init ----------------
__global__ void init_kernel(float* hb0, int* word_buf, int* hsrc) {
  int i = blockIdx.x * 256 + threadIdx.x;
  if (i < 32 * 512) hb0[i] = 0.f;
  if (i < 160) { word_buf[i] = 0; hsrc[i] = i / KBM; }
}

// ---------------- batched encoder gi: rows r = s*32+b, token = source[b*32+s] ----
// grid (96, 8): j-tile 16, m-tile 128. 256 thr: ng=tid&7 (2 j), mg=tid>>3 (4 rows).
// No bias (added in hupd). Software-pipelined 1 chunk ahead.
__global__ __launch_bounds__(256, 4) void genc_kernel(
    const float* __restrict__ emb, const int* __restrict__ source,
    const float* __restrict__ Wih, float* __restrict__ gi_enc)
{
  const int tid = threadIdx.x;
  const int ng = tid & 7;
  const int mg = tid >> 3;
  const int j0 = blockIdx.x * 16 + ng * 2;
  const int r0 = blockIdx.y * 128 + mg * 4;

  const float* arow[4];
  #pragma unroll
  for (int i = 0; i < 4; i++) {
    int r = r0 + i;
    int tok = source[(r & 31) * 32 + (r >> 5)];
    arow[i] = emb + (long)tok * 512;
  }
  const float* w0p = Wih + (long)j0 * 512;
  const float* w1p = w0p + 512;

  float acc0[4], acc1[4];
  #pragma unroll
  for (int i = 0; i < 4; i++) { acc0[i] = 0.f; acc1[i] = 0.f; }

  float4 wc0 = *(const float4*)w0p;
  float4 wc1 = *(const float4*)w1p;
  float4 ac[4];
  #pragma unroll
  for (int i = 0; i < 4; i++) ac[i] = *(const float4*)arow[i];

  for (int k = 0; k < 508; k += 4) {
    float4 wn0 = *(const float4*)(w0p + k + 4);
    float4 wn1 = *(const float4*)(w1p + k + 4);
    float4 an[4];
    #pragma unroll
    for (int i = 0; i < 4; i++) an[i] = *(const float4*)(arow[i] + k + 4);
    #pragma unroll
    for (int i = 0; i < 4; i++) {
      acc0[i] += ac[i].x * wc0.x + ac[i].y * wc0.y + ac[i].z * wc0.z + ac[i].w * wc0.w;
      acc1[i] += ac[i].x * wc1.x + ac[i].y * wc1.y + ac[i].z * wc1.z + ac[i].w * wc1.w;
    }
    wc0 = wn0; wc1 = wn1;
    #pragma unroll
    for (int i = 0; i < 4; i++) ac[i] = an[i];
  }
  #pragma unroll
  for (int i = 0; i < 4; i++) {
    acc0[i] += ac[i].x * wc0.x + ac[i].y * wc0.y + ac[i].z * wc0.z + ac[i].w * wc0.w;
    acc1[i] += ac[i].x * wc1.x + ac[i].y * wc1.y + ac[i].z * wc1.z + ac[i].w * wc1.w;
  }
  #pragma unroll
  for (int i = 0; i < 4; i++) {
    float2 r; r.x = acc0[i]; r.y = acc1[i];
    *(float2*)(gi_enc + (long)(r0 + i) * 1536 + j0) = r;
  }
}

// ---------------- gates GEMM, K-split 4, no bias (bias in hupd) ----------------
// grid (96, HONLY?1:2, 4). 256 thr: ng=tid&7 (2 j), mg=tid>>3 (P rows each).
// Each z-block computes K range [z*128, z*128+128) into partial buffer z.
template<int P, int HONLY>
__global__ __launch_bounds__(256, 4) void gates_kernel(
    const float* __restrict__ emb, const int* __restrict__ tok_ptr, int tok_stride,
    const float* __restrict__ hbuf, const int* __restrict__ hsrc,
    const float* __restrict__ Wih, const float* __restrict__ Whh,
    float* __restrict__ gip, float* __restrict__ ghp)
{
  const bool is_h = HONLY ? true : (blockIdx.y != 0);
  const float* W = is_h ? Whh : Wih;
  const int M = 32 * P;
  float* out = (is_h ? ghp : gip) + (long)blockIdx.z * M * 1536;

  const int tid = threadIdx.x;
  const int ng = tid & 7;
  const int mg = tid >> 3;
  const int j0 = blockIdx.x * 16 + ng * 2;
  const int k0 = blockIdx.z * 128;

  const float* arow[P];
  #pragma unroll
  for (int i = 0; i < P; i++) {
    int m = mg * P + i;
    if (is_h) { int r = hsrc ? hsrc[m] : m; arow[i] = hbuf + (long)r * 512 + k0; }
    else      { int tk = tok_ptr[m * tok_stride]; arow[i] = emb + (long)tk * 512 + k0; }
  }
  const float* w0p = W + (long)j0 * 512 + k0;
  const float* w1p = w0p + 512;

  float acc0[P], acc1[P];
  #pragma unroll
  for (int i = 0; i < P; i++) { acc0[i] = 0.f; acc1[i] = 0.f; }

  float4 wc0 = *(const float4*)w0p;
  float4 wc1 = *(const float4*)w1p;
  float4 ac[P];
  #pragma unroll
  for (int i = 0; i < P; i++) ac[i] = *(const float4*)arow[i];

  for (int k = 0; k < 124; k += 4) {
    float4 wn0 = *(const float4*)(w0p + k + 4);
    float4 wn1 = *(const float4*)(w1p + k + 4);
    float4 an[P];
    #pragma unroll
    for (int i = 0; i < P; i++) an[i] = *(const float4*)(arow[i] + k + 4);
    #pragma unroll
    for (int i = 0; i < P; i++) {
      acc0[i] += ac[i].x * wc0.x + ac[i].y * wc0.y + ac[i].z * wc0.z + ac[i].w * wc0.w;
      acc1[i] += ac[i].x * wc1.x + ac[i].y * wc1.y + ac[i].z * wc1.z + ac[i].w * wc1.w;
    }
    wc0 = wn0; wc1 = wn1;
    #pragma unroll
    for (int i = 0; i < P; i++) ac[i] = an[i];
  }
  #pragma unroll
  for (int i = 0; i < P; i++) {
    acc0[i] += ac[i].x * wc0.x + ac[i].y * wc0.y + ac[i].z * wc0.z + ac[i].w * wc0.w;
    acc1[i] += ac[i].x * wc1.x + ac[i].y * wc1.y + ac[i].z * wc1.z + ac[i].w * wc1.w;
  }
  #pragma unroll
  for (int i = 0; i < P; i++) {
    int m = mg * P + i;
    float2 r; r.x = acc0[i]; r.y = acc1[i];
    *(float2*)(out + (long)m * 1536 + j0) = r;
  }
}

// ---------------- GRU elementwise update (sums K-split partials, adds biases) ----
template<int NPI, int NPH, int M>
__global__ __launch_bounds__(256) void hupd_kernel(
    const float* __restrict__ gip, const float* __restrict__ ghp,
    const float* __restrict__ bih, const float* __restrict__ bhh,
    const float* __restrict__ hin, const int* __restrict__ hsrc,
    float* __restrict__ hout)
{
  int idx = blockIdx.x * 256 + threadIdx.x;
  if (idx >= M * 512) return;
  int m = idx >> 9, i = idx & 511;
  float ir = 0.f, iz = 0.f, inn = 0.f, hr = 0.f, hz = 0.f, hn = 0.f;
  #pragma unroll
  for (int p = 0; p < NPI; p++) {
    const float* g = gip + (long)p * M * 1536 + (long)m * 1536;
    ir += g[i]; iz += g[512 + i]; inn += g[1024 + i];
  }
  #pragma unroll
  for (int p = 0; p < NPH; p++) {
    const float* g = ghp + (long)p * M * 1536 + (long)m * 1536;
    hr += g[i]; hz += g[512 + i]; hn += g[1024 + i];
  }
  ir += bih[i]; iz += bih[512 + i]; inn += bih[1024 + i];
  hr += bhh[i]; hz += bhh[512 + i]; hn += bhh[1024 + i];
  float r = 1.f / (1.f + expf(-(ir + hr)));
  float z = 1.f / (1.f + expf(-(iz + hz)));
  float n = tanhf(inn + r * hn);
  int src = hsrc ? hsrc[m] : m;
  float h = hin[(long)src * 512 + i];
  hout[(long)m * 512 + i] = (1.f - z) * n + z * h;
}

// ---------------- fused logits + per-block (lse-partial, top5-partial) ----------
// grid NVBLK=1000 (32 v each). 256 thr: ng=tid&7 (4 v), mg=tid>>3 (5 rows).
// GEMM software-pipelined 1 chunk ahead; result -> LDS transpose; threads
// 0..159 reduce their row's 32 values to (max, sumexp, top5) partials.
__global__ __launch_bounds__(256, 4) void logtop_kernel(
    const float* __restrict__ h1, const float* __restrict__ Wout,
    const float* __restrict__ bout,
    float* __restrict__ pms, float* __restrict__ pv, int* __restrict__ pi)
{
  const int tid = threadIdx.x;
  const int ng = tid & 7;
  const int mg = tid >> 3;
  const int blk = blockIdx.x;
  const int v = blk * 32 + ng * 4;
  const int m0 = mg * 5;

  const float* a0 = h1 + (long)m0 * 512;
  const float* wp = Wout + v;

  float4 acc[5];
  #pragma unroll
  for (int i = 0; i < 5; i++) acc[i] = make_float4(0.f, 0.f, 0.f, 0.f);

  float4 wc[4], ac[5];
  #pragma unroll
  for (int j = 0; j < 4; j++) wc[j] = *(const float4*)(wp + (long)j * VSZ);
  #pragma unroll
  for (int i = 0; i < 5; i++) ac[i] = *(const float4*)(a0 + i * 512);

  for (int k = 0; k < 508; k += 4) {
    float4 wn[4], an[5];
    #pragma unroll
    for (int j = 0; j < 4; j++) wn[j] = *(const float4*)(wp + (long)(k + 4 + j) * VSZ);
    #pragma unroll
    for (int i = 0; i < 5; i++) an[i] = *(const float4*)(a0 + i * 512 + k + 4);
    #pragma unroll
    for (int i = 0; i < 5; i++) {
      acc[i].x += ac[i].x * wc[0].x + ac[i].y * wc[1].x + ac[i].z * wc[2].x + ac[i].w * wc[3].x;
      acc[i].y += ac[i].x * wc[0].y + ac[i].y * wc[1].y + ac[i].z * wc[2].y + ac[i].w * wc[3].y;
      acc[i].z += ac[i].x * wc[0].z + ac[i].y * wc[1].z + ac[i].z * wc[2].z + ac[i].w * wc[3].z;
      acc[i].w += ac[i].x * wc[0].w + ac[i].y * wc[1].w + ac[i].z * wc[2].w + ac[i].w * wc[3].w;
    }
    #pragma unroll
    for (int j = 0; j < 4; j++) wc[j] = wn[j];
    #pragma unroll
    for (int i = 0; i < 5; i++) ac[i] = an[i];
  }
  #pragma unroll
  for (int i = 0; i < 5; i++) {
    acc[i].x += ac[i].x * wc[0].x + ac[i].y * wc[1].x + ac[i].z * wc[2].x + ac[i].w * wc[3].x;
    acc[i].y += ac[i].x * wc[0].y + ac[i].y * wc[1].y + ac[i].z * wc[2].y + ac[i].w * wc[3].y;
    acc[i].z += ac[i].x * wc[0].z + ac[i].y * wc[1].z + ac[i].z * wc[2].z + ac[i].w * wc[3].z;
    acc[i].w += ac[i].x * wc[0].w + ac[i].y * wc[1].w + ac[i].z * wc[2].w + ac[i].w * wc[3].w;
  }

  __shared__ float L[160][33];
  float4 bb = *(const float4*)(bout + v);
  #pragma unroll
  for (int i = 0; i < 5; i++) {
    L[m0 + i][ng * 4 + 0] = acc[i].x + bb.x;
    L[m0 + i][ng * 4 + 1] = acc[i].y + bb.y;
    L[m0 + i][ng * 4 + 2] = acc[i].z + bb.z;
    L[m0 + i][ng * 4 + 3] = acc[i].w + bb.w;
  }
  __syncthreads();

  if (tid < 160) {
    float m = -3.4e38f, s = 0.f;
    float tv0 = -3.4e38f, tv1 = -3.4e38f, tv2 = -3.4e38f, tv3 = -3.4e38f, tv4 = -3.4e38f;
    int ti0 = 0x7fffffff, ti1 = 0x7fffffff, ti2 = 0x7fffffff, ti3 = 0x7fffffff, ti4 = 0x7fffffff;
    int base = blk * 32;
    for (int c = 0; c < 32; c++) {
      float x = L[tid][c];
      if (x > m) { s *= expf(m - x); m = x; }
      s += expf(x - m);
      INS5(x, base + c);
    }
    long o = (long)blk * 160 + tid;
    pms[o * 2 + 0] = m; pms[o * 2 + 1] = s;
    pv[o * 5 + 0] = tv0; pi[o * 5 + 0] = ti0;
    pv[o * 5 + 1] = tv1; pi[o * 5 + 1] = ti1;
    pv[o * 5 + 2] = tv2; pi[o * 5 + 2] = ti2;
    pv[o * 5 + 3] = tv3; pi[o * 5 + 3] = ti3;
    pv[o * 5 + 4] = tv4; pi[o * 5 + 4] = ti4;
  }
}

// ---------------- merge 1000 partials per row -> lse, top5 ----------------
__global__ __launch_bounds__(256) void merge_kernel(
    const float* __restrict__ pms, const float* __restrict__ pv,
    const int* __restrict__ pi, float* __restrict__ lse,
    float* __restrict__ rv5, int* __restrict__ ri5)
{
  int row = blockIdx.x, tid = threadIdx.x;
  float m = -3.4e38f, s = 0.f;
  float tv0 = -3.4e38f, tv1 = -3.4e38f, tv2 = -3.4e38f, tv3 = -3.4e38f, tv4 = -3.4e38f;
  int ti0 = 0x7fffffff, ti1 = 0x7fffffff, ti2 = 0x7fffffff, ti3 = 0x7fffffff, ti4 = 0x7fffffff;

  for (int blk = tid; blk < NVBLK; blk += 256) {
    long o = (long)blk * 160 + row;
    float bm = pms[o * 2 + 0], bs = pms[o * 2 + 1];
    float nm = fmaxf(m, bm);
    s = s * expf(m - nm) + bs * expf(bm - nm);
    m = nm;
    float xv; int xi;
    xv = pv[o * 5 + 0]; xi = pi[o * 5 + 0]; INS5(xv, xi);
    xv = pv[o * 5 + 1]; xi = pi[o * 5 + 1]; INS5(xv, xi);
    xv = pv[o * 5 + 2]; xi = pi[o * 5 + 2]; INS5(xv, xi);
    xv = pv[o * 5 + 3]; xi = pi[o * 5 + 3]; INS5(xv, xi);
    xv = pv[o * 5 + 4]; xi = pi[o * 5 + 4]; INS5(xv, xi);
  }
  for (int mask = 1; mask < 64; mask <<= 1) {
    float om = __shfl_xor(m, mask, 64);
    float os = __shfl_xor(s, mask, 64);
    float nm = fmaxf(m, om);
    s = s * expf(m - nm) + os * expf(om - nm);
    m = nm;
  }
  __shared__ float sm[4], ss[4];
  __shared__ float sv[256 * 5];
  __shared__ int   si[256 * 5];
  if ((tid & 63) == 0) { sm[tid >> 6] = m; ss[tid >> 6] = s; }
  sv[tid * 5 + 0] = tv0; si[tid * 5 + 0] = ti0;
  sv[tid * 5 + 1] = tv1; si[tid * 5 + 1] = ti1;
  sv[tid * 5 + 2] = tv2; si[tid * 5 + 2] = ti2;
  sv[tid * 5 + 3] = tv3; si[tid * 5 + 3] = ti3;
  sv[tid * 5 + 4] = tv4; si[tid * 5 + 4] = ti4;
  __syncthreads();
  if (tid == 0) {
    float M2 = sm[0], S2 = ss[0];
    for (int w = 1; w < 4; w++) {
      float nm = fmaxf(M2, sm[w]);
      S2 = S2 * expf(M2 - nm) + ss[w] * expf(sm[w] - nm);
      M2 = nm;
    }
    lse[row] = M2 + logf(S2);
  }
  for (int str = 128; str >= 1; str >>= 1) {
    if (tid < str) {
      float* av = &sv[tid * 5];         int* ai = &si[tid * 5];
      float* bv = &sv[(tid + str) * 5]; int* bi = &si[(tid + str) * 5];
      float o0[5]; int o1[5];
      int i = 0, j = 0;
      #pragma unroll
      for (int o = 0; o < 5; o++) {
        float avv = av[i]; int aii = ai[i];
        float bvv = bv[j]; int bii = bi[j];
        bool ta = cand_gt(avv, aii, bvv, bii);
        o0[o] = ta ? avv : bvv; o1[o] = ta ? aii : bii;
        i += ta ? 1 : 0; j += ta ? 0 : 1;
      }
      #pragma unroll
      for (int o = 0; o < 5; o++) { av[o] = o0[o]; ai[o] = o1[o]; }
    }
    __syncthreads();
  }
  if (tid == 0) {
    #pragma unroll
    for (int o = 0; o < 5; o++) { rv5[row * 5 + o] = sv[o]; ri5[row * 5 + o] = si[o]; }
  }
}

// ---------------- step-0 bookkeeping (row b*KBM only, a = 0) -----------
__global__ void book0_kernel(const float* __restrict__ rv5, const int* __restrict__ ri5,
                             const float* __restrict__ lse,
                             int* __restrict__ seqs, float* __restrict__ act_ll,
                             int* __restrict__ word_buf, int* __restrict__ hsrc,
                             float* __restrict__ best_ll, int* __restrict__ best_seq)
{
  int b = blockIdx.x, tid = threadIdx.x;
  int row = b * KBM;
  float l = lse[row];
  if (tid < SEQL) {
    for (int j = 0; j < KBM; j++) {
      int w = ri5[row * 5 + j];
      seqs[(b * KBM + j) * SEQL + tid] = (tid == 0) ? 0 : (tid == 1 ? w : 2);
    }
    best_seq[b * SEQL + tid] = 2;
  }
  if (tid < KBM) {
    act_ll[b * KBM + tid] = rv5[row * 5 + tid] - l;
    word_buf[b * KBM + tid] = ri5[row * 5 + tid];
    hsrc[b * KBM + tid] = b * KBM + tid;
  }
  if (tid == 0) best_ll[b] = NEGF;
}

// ---------------- per-step bookkeeping (25-candidate merge folded in) ------------
__global__ void book_kernel(const float* __restrict__ rv5, const int* __restrict__ ri5,
                            const float* __restrict__ lse,
                            const int* __restrict__ seqs_old, int* __restrict__ seqs_new,
                            float* __restrict__ act_ll, int* __restrict__ word_buf,
                            int* __restrict__ hsrc, float* __restrict__ best_ll,
                            int* __restrict__ best_seq, int t)
{
  int b = blockIdx.x, tid = threadIdx.x;
  __shared__ float sv5[5];
  __shared__ int   si5[5];
  if (tid == 0) {
    float tv0 = -3.4e38f, tv1 = -3.4e38f, tv2 = -3.4e38f, tv3 = -3.4e38f, tv4 = -3.4e38f;
    int ti0 = 0x7fffffff, ti1 = 0x7fffffff, ti2 = 0x7fffffff, ti3 = 0x7fffffff, ti4 = 0x7fffffff;
    for (int k = 0; k < KBM; k++) {
      int row = b * KBM + k;
      float a = act_ll[row], l = lse[row];
      #pragma unroll
      for (int j = 0; j < 5; j++) {
        float x = a + (rv5[row * 5 + j] - l);
        int id = k * VSZ + ri5[row * 5 + j];
        INS5(x, id);
      }
    }
    sv5[0] = tv0; si5[0] = ti0; sv5[1] = tv1; si5[1] = ti1;
    sv5[2] = tv2; si5[2] = ti2; sv5[3] = tv3; si5[3] = ti3;
    sv5[4] = tv4; si5[4] = ti4;
  }
  __syncthreads();

  __shared__ int ls[KBM][SEQL];
  float v[KBM]; int pr[KBM], wd[KBM];
  #pragma unroll
  for (int j = 0; j < KBM; j++) {
    v[j] = sv5[j];
    int id = si5[j];
    pr[j] = id / VSZ; wd[j] = id % VSZ;
  }
  #pragma unroll
  for (int j = 0; j < KBM; j++) {
    if (tid < SEQL) {
      int x = (tid == t + 1) ? wd[j] : seqs_old[(b * KBM + pr[j]) * SEQL + tid];
      ls[j][tid] = x;
      seqs_new[(b * KBM + j) * SEQL + tid] = x;
    }
  }
  __syncthreads();
  float cll[KBM];
  #pragma unroll
  for (int j = 0; j < KBM; j++) {
    bool fin = v[j] > FINTH;
    bool eos = (wd[j] == 1) && fin;
    cll[j] = eos ? v[j] / (float)(t + 2) : NEGF;
  }
  int jb = 0; float cb = cll[0];
  #pragma unroll
  for (int j = 1; j < KBM; j++) if (cll[j] > cb) { cb = cll[j]; jb = j; }
  bool improve = cb > best_ll[b];
  if (improve) {
    if (tid == 0) best_ll[b] = cb;
    if (tid < SEQL) best_seq[b * SEQL + tid] = ls[jb][tid];
  }
  if (tid < KBM) {
    int j = tid;
    bool fin = v[j] > FINTH;
    bool eos = (wd[j] == 1) && fin;
    act_ll[b * KBM + j] = (fin && !eos) ? v[j] : NEGF;
    word_buf[b * KBM + j] = wd[j];
    hsrc[b * KBM + j] = b * KBM + pr[j];
  }
}

// ---------------- winner selection ----------------
__global__ void final_kernel(const float* __restrict__ best_ll, const int* __restrict__ best_seq,
                             const float* __restrict__ act_ll, const int* __restrict__ seqs,
                             int* __restrict__ out)
{
  int b = blockIdx.x, tid = threadIdx.x;
  bool have = best_ll[b] > FINTH;
  int jb = 0; float ab = act_ll[b * KBM];
  for (int j = 1; j < KBM; j++)
    if (act_ll[b * KBM + j] > ab) { ab = act_ll[b * KBM + j]; jb = j; }
  if (tid < SEQL)
    out[b * SEQL + tid] = have ? best_seq[b * SEQL + tid]
                               : seqs[(b * KBM + jb) * SEQL + tid];
}

extern "C" void kernel_launch(void* const* d_in, const int* in_sizes, int n_in,
                              void* d_out, int out_size, void* d_ws, size_t ws_size,
                              hipStream_t stream)
{
  const int*   source  = (const int*)d_in[0];
  const float* emb_src = (const float*)d_in[1];
  const float* emb_tgt = (const float*)d_in[2];
  const float* eWih = (const float*)d_in[3];
  const float* eWhh = (const float*)d_in[4];
  const float* ebih = (const float*)d_in[5];
  const float* ebhh = (const float*)d_in[6];
  const float* dWih = (const float*)d_in[7];
  const float* dWhh = (const float*)d_in[8];
  const float* dbih = (const float*)d_in[9];
  const float* dbhh = (const float*)d_in[10];
  const float* Wout = (const float*)d_in[11];
  const float* bout = (const float*)d_in[12];
  int* out = (int*)d_out;

  char* ws = (char*)d_ws;
  size_t off = 0;
  auto alloc = [&](size_t bytes) {
    void* p = ws + off;
    off = (off + bytes + 255) & ~(size_t)255;
    return p;
  };
  float* hb0     = (float*)alloc(160 * 512 * 4);
  float* hb1     = (float*)alloc(160 * 512 * 4);
  float* gip     = (float*)alloc((size_t)4 * 160 * 1536 * 4);
  float* ghp     = (float*)alloc((size_t)4 * 160 * 1536 * 4);
  char*  uni     = (char*) alloc((size_t)8 * 1024 * 1024);   // gi_enc aliases partials
  float* gi_enc  = (float*)uni;                              // 1024*1536*4 = 6.29 MB
  float* pms     = (float*)uni;                              // 1000*160*2*4 = 1.28 MB
  float* pv      = (float*)(uni + 1536 * 1024);              // 1000*160*5*4 = 3.20 MB
  int*   pi      = (int*)  (uni + 1536 * 1024 + 3328 * 1024);
  float* lse     = (float*)alloc(160 * 4);
  float* act_ll  = (float*)alloc(160 * 4);
  float* rv5     = (float*)alloc(160 * 5 * 4);
  float* best_ll = (float*)alloc(32 * 4);
  int*   ri5     = (int*)alloc(160 * 5 * 4);
  int*   seqs0   = (int*)alloc(160 * SEQL * 4);
  int*   seqs1   = (int*)alloc(160 * SEQL * 4);
  int*   wordb   = (int*)alloc(160 * 4);
  int*   hsrc    = (int*)alloc(160 * 4);
  int*   bseq    = (int*)alloc(32 * SEQL * 4);

  init_kernel<<<64, 256, 0, stream>>>(hb0, wordb, hsrc);

  // ---- encoder: batched gi for all 32 steps, then serial gh + update ----
  genc_kernel<<<dim3(96, 8), 256, 0, stream>>>(emb_src, source, eWih, gi_enc);
  for (int s = 0; s < 32; s++) {
    gates_kernel<1, 1><<<dim3(96, 1, 4), 256, 0, stream>>>(
        nullptr, nullptr, 0, hb0, nullptr, nullptr, eWhh, nullptr, ghp);
    hupd_kernel<1, 4, 32><<<64, 256, 0, stream>>>(
        gi_enc + (size_t)s * 32 * 1536, ghp, ebih, ebhh, hb0, nullptr, hb0);
  }

  // ---- decode step 0 (initial advance) ----
  gates_kernel<5, 0><<<dim3(96, 2, 4), 256, 0, stream>>>(
      emb_tgt, wordb, 1, hb0, hsrc, dWih, dWhh, gip, ghp);
  hupd_kernel<4, 4, 160><<<320, 256, 0, stream>>>(
      gip, ghp, dbih, dbhh, hb0, hsrc, hb1);
  logtop_kernel<<<NVBLK, 256, 0, stream>>>(hb1, Wout, bout, pms, pv, pi);
  merge_kernel<<<160, 256, 0, stream>>>(pms, pv, pi, lse, rv5, ri5);
  book0_kernel<<<32, 64, 0, stream>>>(rv5, ri5, lse, seqs0, act_ll, wordb, hsrc,
                                      best_ll, bseq);

  // ---- decode steps t = 1..32 ----
  float* hcur = hb1; float* hoth = hb0;
  int* scur = seqs0; int* soth = seqs1;
  for (int t = 1; t <= 32; t++) {
    gates_kernel<5, 0><<<dim3(96, 2, 4), 256, 0, stream>>>(
        emb_tgt, wordb, 1, hcur, hsrc, dWih, dWhh, gip, ghp);
    hupd_kernel<4, 4, 160><<<320, 256, 0, stream>>>(
        gip, ghp, dbih, dbhh, hcur, hsrc, hoth);
    logtop_kernel<<<NVBLK, 256, 0, stream>>>(hoth, Wout, bout, pms, pv, pi);
    merge_kernel<<<160, 256, 0, stream>>>(pms, pv, pi, lse, rv5, ri5);
    book_kernel<<<32, 64, 0, stream>>>(rv5, ri5, lse, scur, soth, act_ll, wordb,
                                       hsrc, best_ll, bseq, t);
    { float* tmp = hcur; hcur = hoth; hoth = tmp; }
    { int* tmp = scur; scur = soth; soth = tmp; }
  }

  final_kernel<<<32, 64, 0, stream>>>(best_ll, bseq, act_ll, scur, out);
}

// Round 3
// 6885.826 us; speedup vs baseline: 1.6331x; 1.1871x over previous
//
#include <hip/hip_runtime.h>
#include <math.h>

#define NEGF   (-1e30f)
#define FINTH  (-5e29f)
#define VSZ    32000
#define KBM    5
#define SEQL   34   // T+1 where T = 33
#define NVBLK  1000 // logtop blocks (32 v each)

__device__ __forceinline__ bool cand_gt(float av, int ai, float bv, int bi) {
  return (av > bv) || (av == bv && ai < bi);
}

// top-5 insertion, maintains (tv0..tv4, ti0..ti4) sorted desc by (val, -idx)
#define INS5(xx, ii)                                                           \
  if (cand_gt(xx, ii, tv4, ti4)) {                                             \
    tv4 = xx; ti4 = ii;                                                        \
    if (cand_gt(tv4, ti4, tv3, ti3)) { float tf = tv3; int tj = ti3; tv3 = tv4; ti3 = ti4; tv4 = tf; ti4 = tj; \
      if (cand_gt(tv3, ti3, tv2, ti2)) { tf = tv2; tj = ti2; tv2 = tv3; ti2 = ti3; tv3 = tf; ti3 = tj; \
        if (cand_gt(tv2, ti2, tv1, ti1)) { tf = tv1; tj = ti1; tv1 = tv2; ti1 = ti2; tv2 = tf; ti2 = tj; \
          if (cand_gt(tv1, ti1, tv0, ti0)) { tf = tv0; tj = ti0; tv0 = tv1; ti0 = ti1; tv1 = tf; ti1 = tj; } } } } }

// ---------------- init ----------------
__global__ void init_kernel(float* hb0, int* word_buf, int* hsrc) {
  int i = blockIdx.x * 256 + threadIdx.x;
  if (i < 32 * 512) hb0[i] = 0.f;
  if (i < 160) { word_buf[i] = 0; hsrc[i] = i / KBM; }
}

// ---------------- batched encoder gi: rows r = s*32+b, token = source[b*32+s] ----
__global__ __launch_bounds__(256, 4) void genc_kernel(
    const float* __restrict__ emb, const int* __restrict__ source,
    const float* __restrict__ Wih, float* __restrict__ gi_enc)
{
  const int tid = threadIdx.x;
  const int ng = tid & 7;
  const int mg = tid >> 3;
  const int j0 = blockIdx.x * 16 + ng * 2;
  const int r0 = blockIdx.y * 128 + mg * 4;

  const float* arow[4];
  #pragma unroll
  for (int i = 0; i < 4; i++) {
    int r = r0 + i;
    int tok = source[(r & 31) * 32 + (r >> 5)];
    arow[i] = emb + (long)tok * 512;
  }
  const float* w0p = Wih + (long)j0 * 512;
  const float* w1p = w0p + 512;

  float acc0[4], acc1[4];
  #pragma unroll
  for (int i = 0; i < 4; i++) { acc0[i] = 0.f; acc1[i] = 0.f; }

  float4 wc0 = *(const float4*)w0p;
  float4 wc1 = *(const float4*)w1p;
  float4 ac[4];
  #pragma unroll
  for (int i = 0; i < 4; i++) ac[i] = *(const float4*)arow[i];

  for (int k = 0; k < 508; k += 4) {
    float4 wn0 = *(const float4*)(w0p + k + 4);
    float4 wn1 = *(const float4*)(w1p + k + 4);
    float4 an[4];
    #pragma unroll
    for (int i = 0; i < 4; i++) an[i] = *(const float4*)(arow[i] + k + 4);
    #pragma unroll
    for (int i = 0; i < 4; i++) {
      acc0[i] += ac[i].x * wc0.x + ac[i].y * wc0.y + ac[i].z * wc0.z + ac[i].w * wc0.w;
      acc1[i] += ac[i].x * wc1.x + ac[i].y * wc1.y + ac[i].z * wc1.z + ac[i].w * wc1.w;
    }
    wc0 = wn0; wc1 = wn1;
    #pragma unroll
    for (int i = 0; i < 4; i++) ac[i] = an[i];
  }
  #pragma unroll
  for (int i = 0; i < 4; i++) {
    acc0[i] += ac[i].x * wc0.x + ac[i].y * wc0.y + ac[i].z * wc0.z + ac[i].w * wc0.w;
    acc1[i] += ac[i].x * wc1.x + ac[i].y * wc1.y + ac[i].z * wc1.z + ac[i].w * wc1.w;
  }
  #pragma unroll
  for (int i = 0; i < 4; i++) {
    float2 r; r.x = acc0[i]; r.y = acc1[i];
    *(float2*)(gi_enc + (long)(r0 + i) * 1536 + j0) = r;
  }
}

// ---------------- gates GEMM, K-split 4, no bias (bias in hupd) ----------------
template<int P, int HONLY>
__global__ __launch_bounds__(256, 4) void gates_kernel(
    const float* __restrict__ emb, const int* __restrict__ tok_ptr, int tok_stride,
    const float* __restrict__ hbuf, const int* __restrict__ hsrc,
    const float* __restrict__ Wih, const float* __restrict__ Whh,
    float* __restrict__ gip, float* __restrict__ ghp)
{
  const bool is_h = HONLY ? true : (blockIdx.y != 0);
  const float* W = is_h ? Whh : Wih;
  const int M = 32 * P;
  float* out = (is_h ? ghp : gip) + (long)blockIdx.z * M * 1536;

  const int tid = threadIdx.x;
  const int ng = tid & 7;
  const int mg = tid >> 3;
  const int j0 = blockIdx.x * 16 + ng * 2;
  const int k0 = blockIdx.z * 128;

  const float* arow[P];
  #pragma unroll
  for (int i = 0; i < P; i++) {
    int m = mg * P + i;
    if (is_h) { int r = hsrc ? hsrc[m] : m; arow[i] = hbuf + (long)r * 512 + k0; }
    else      { int tk = tok_ptr[m * tok_stride]; arow[i] = emb + (long)tk * 512 + k0; }
  }
  const float* w0p = W + (long)j0 * 512 + k0;
  const float* w1p = w0p + 512;

  float acc0[P], acc1[P];
  #pragma unroll
  for (int i = 0; i < P; i++) { acc0[i] = 0.f; acc1[i] = 0.f; }

  float4 wc0 = *(const float4*)w0p;
  float4 wc1 = *(const float4*)w1p;
  float4 ac[P];
  #pragma unroll
  for (int i = 0; i < P; i++) ac[i] = *(const float4*)arow[i];

  for (int k = 0; k < 124; k += 4) {
    float4 wn0 = *(const float4*)(w0p + k + 4);
    float4 wn1 = *(const float4*)(w1p + k + 4);
    float4 an[P];
    #pragma unroll
    for (int i = 0; i < P; i++) an[i] = *(const float4*)(arow[i] + k + 4);
    #pragma unroll
    for (int i = 0; i < P; i++) {
      acc0[i] += ac[i].x * wc0.x + ac[i].y * wc0.y + ac[i].z * wc0.z + ac[i].w * wc0.w;
      acc1[i] += ac[i].x * wc1.x + ac[i].y * wc1.y + ac[i].z * wc1.z + ac[i].w * wc1.w;
    }
    wc0 = wn0; wc1 = wn1;
    #pragma unroll
    for (int i = 0; i < P; i++) ac[i] = an[i];
  }
  #pragma unroll
  for (int i = 0; i < P; i++) {
    acc0[i] += ac[i].x * wc0.x + ac[i].y * wc0.y + ac[i].z * wc0.z + ac[i].w * wc0.w;
    acc1[i] += ac[i].x * wc1.x + ac[i].y * wc1.y + ac[i].z * wc1.z + ac[i].w * wc1.w;
  }
  #pragma unroll
  for (int i = 0; i < P; i++) {
    int m = mg * P + i;
    float2 r; r.x = acc0[i]; r.y = acc1[i];
    *(float2*)(out + (long)m * 1536 + j0) = r;
  }
}

// ---------------- GRU elementwise update (sums K-split partials, adds biases) ----
template<int NPI, int NPH, int M>
__global__ __launch_bounds__(256) void hupd_kernel(
    const float* __restrict__ gip, const float* __restrict__ ghp,
    const float* __restrict__ bih, const float* __restrict__ bhh,
    const float* __restrict__ hin, const int* __restrict__ hsrc,
    float* __restrict__ hout)
{
  int idx = blockIdx.x * 256 + threadIdx.x;
  if (idx >= M * 512) return;
  int m = idx >> 9, i = idx & 511;
  float ir = 0.f, iz = 0.f, inn = 0.f, hr = 0.f, hz = 0.f, hn = 0.f;
  #pragma unroll
  for (int p = 0; p < NPI; p++) {
    const float* g = gip + (long)p * M * 1536 + (long)m * 1536;
    ir += g[i]; iz += g[512 + i]; inn += g[1024 + i];
  }
  #pragma unroll
  for (int p = 0; p < NPH; p++) {
    const float* g = ghp + (long)p * M * 1536 + (long)m * 1536;
    hr += g[i]; hz += g[512 + i]; hn += g[1024 + i];
  }
  ir += bih[i]; iz += bih[512 + i]; inn += bih[1024 + i];
  hr += bhh[i]; hz += bhh[512 + i]; hn += bhh[1024 + i];
  float r = 1.f / (1.f + expf(-(ir + hr)));
  float z = 1.f / (1.f + expf(-(iz + hz)));
  float n = tanhf(inn + r * hn);
  int src = hsrc ? hsrc[m] : m;
  float h = hin[(long)src * 512 + i];
  hout[(long)m * 512 + i] = (1.f - z) * n + z * h;
}

// ---------------- fused logits + per-block (lse-partial, top5-partial) ----------
// grid NVBLK=1000 (32 v each). 256 thr: ng=tid&7 (4 v), mg=tid>>3 (5 rows).
// W staged via global_load_lds into double-buffered 64k x 32v LDS tiles (8 KB),
// one __syncthreads per tile (compute 2560 cy >> staging latency). W consumed
// via conflict-free ds_read_b128; A (h1, L2-hot) via ping-pong register loads.
__global__ __launch_bounds__(256, 4) void logtop_kernel(
    const float* __restrict__ h1, const float* __restrict__ Wout,
    const float* __restrict__ bout,
    float* __restrict__ pms, float* __restrict__ pv, int* __restrict__ pi)
{
  const int tid = threadIdx.x;
  const int ng = tid & 7;
  const int mg = tid >> 3;
  const int blk = blockIdx.x;
  const int v0 = blk * 32;
  const int v = v0 + ng * 4;
  const int m0 = mg * 5;

  __shared__ float Wlds[2][2048];   // [buf][64 k rows x 32 v]
  __shared__ float L[160][33];

  const float* a0 = h1 + (long)m0 * 512;

  // staging: flat idx = tid (rows 0..31) and tid+256 (rows 32..63) of the tile.
  // LDS dest is wave-uniform base + lane*16B -> float off tid*4 = [tid>>3][(tid&7)*4].
  const int skk = tid >> 3;
  const int sv4 = tid & 7;
  const float* sg0 = Wout + (size_t)skk * VSZ + v0 + sv4 * 4;
  const float* sg1 = Wout + (size_t)(32 + skk) * VSZ + v0 + sv4 * 4;
  const int lwave = (tid >> 6) * 256;   // this wave's 1KB chunk (in floats)

  auto stage = [&](int tt, int bb) {
    const float* g0 = sg0 + (size_t)tt * 64 * VSZ;
    const float* g1 = sg1 + (size_t)tt * 64 * VSZ;
    __builtin_amdgcn_global_load_lds(
        (const __attribute__((address_space(1))) void*)g0,
        (__attribute__((address_space(3))) void*)&Wlds[bb][lwave], 16, 0, 0);
    __builtin_amdgcn_global_load_lds(
        (const __attribute__((address_space(1))) void*)g1,
        (__attribute__((address_space(3))) void*)&Wlds[bb][1024 + lwave], 16, 0, 0);
  };

  float4 acc[5];
  #pragma unroll
  for (int i = 0; i < 5; i++) acc[i] = make_float4(0.f, 0.f, 0.f, 0.f);

  stage(0, 0);
  __syncthreads();   // drains vmcnt(0) -> tile 0 resident

  float4 aA[5], aB[5];
  #pragma unroll
  for (int i = 0; i < 5; i++) aA[i] = *(const float4*)(a0 + i * 512);

  for (int t8 = 0; t8 < 8; t8++) {
    const float* lb = &Wlds[t8 & 1][0];
    if (t8 < 7) stage(t8 + 1, (t8 + 1) & 1);
    const int kt = t8 * 64;
    #pragma unroll 1
    for (int c = 0; c < 16; c += 2) {
      const int k = kt + c * 4;
      float4 w0[4], w1[4];
      #pragma unroll
      for (int j = 0; j < 4; j++) w0[j] = *(const float4*)&lb[(c * 4 + j) * 32 + ng * 4];
      #pragma unroll
      for (int j = 0; j < 4; j++) w1[j] = *(const float4*)&lb[(c * 4 + 4 + j) * 32 + ng * 4];
      #pragma unroll
      for (int i = 0; i < 5; i++) aB[i] = *(const float4*)(a0 + i * 512 + k + 4);
      #pragma unroll
      for (int i = 0; i < 5; i++) {
        acc[i].x += aA[i].x * w0[0].x + aA[i].y * w0[1].x + aA[i].z * w0[2].x + aA[i].w * w0[3].x;
        acc[i].y += aA[i].x * w0[0].y + aA[i].y * w0[1].y + aA[i].z * w0[2].y + aA[i].w * w0[3].y;
        acc[i].z += aA[i].x * w0[0].z + aA[i].y * w0[1].z + aA[i].z * w0[2].z + aA[i].w * w0[3].z;
        acc[i].w += aA[i].x * w0[0].w + aA[i].y * w0[1].w + aA[i].z * w0[2].w + aA[i].w * w0[3].w;
      }
      int kn = k + 8; if (kn >= 512) kn = 0;   // dummy re-read on last body
      #pragma unroll
      for (int i = 0; i < 5; i++) aA[i] = *(const float4*)(a0 + i * 512 + kn);
      #pragma unroll
      for (int i = 0; i < 5; i++) {
        acc[i].x += aB[i].x * w1[0].x + aB[i].y * w1[1].x + aB[i].z * w1[2].x + aB[i].w * w1[3].x;
        acc[i].y += aB[i].x * w1[0].y + aB[i].y * w1[1].y + aB[i].z * w1[2].y + aB[i].w * w1[3].y;
        acc[i].z += aB[i].x * w1[0].z + aB[i].y * w1[1].z + aB[i].z * w1[2].z + aB[i].w * w1[3].z;
        acc[i].w += aB[i].x * w1[0].w + aB[i].y * w1[1].w + aB[i].z * w1[2].w + aB[i].w * w1[3].w;
      }
    }
    __syncthreads();   // staging for t8+1 landed during the 16-chunk compute
  }

  float4 bb4 = *(const float4*)(bout + v);
  #pragma unroll
  for (int i = 0; i < 5; i++) {
    L[m0 + i][ng * 4 + 0] = acc[i].x + bb4.x;
    L[m0 + i][ng * 4 + 1] = acc[i].y + bb4.y;
    L[m0 + i][ng * 4 + 2] = acc[i].z + bb4.z;
    L[m0 + i][ng * 4 + 3] = acc[i].w + bb4.w;
  }
  __syncthreads();

  if (tid < 160) {
    float m = -3.4e38f, s = 0.f;
    float tv0 = -3.4e38f, tv1 = -3.4e38f, tv2 = -3.4e38f, tv3 = -3.4e38f, tv4 = -3.4e38f;
    int ti0 = 0x7fffffff, ti1 = 0x7fffffff, ti2 = 0x7fffffff, ti3 = 0x7fffffff, ti4 = 0x7fffffff;
    int base = blk * 32;
    for (int c = 0; c < 32; c++) {
      float x = L[tid][c];
      if (x > m) { s *= expf(m - x); m = x; }
      s += expf(x - m);
      INS5(x, base + c);
    }
    long o = (long)blk * 160 + tid;
    pms[o * 2 + 0] = m; pms[o * 2 + 1] = s;
    pv[o * 5 + 0] = tv0; pi[o * 5 + 0] = ti0;
    pv[o * 5 + 1] = tv1; pi[o * 5 + 1] = ti1;
    pv[o * 5 + 2] = tv2; pi[o * 5 + 2] = ti2;
    pv[o * 5 + 3] = tv3; pi[o * 5 + 3] = ti3;
    pv[o * 5 + 4] = tv4; pi[o * 5 + 4] = ti4;
  }
}

// ---------------- merge 1000 partials per row -> lse, top5 ----------------
__global__ __launch_bounds__(256) void merge_kernel(
    const float* __restrict__ pms, const float* __restrict__ pv,
    const int* __restrict__ pi, float* __restrict__ lse,
    float* __restrict__ rv5, int* __restrict__ ri5)
{
  int row = blockIdx.x, tid = threadIdx.x;
  float m = -3.4e38f, s = 0.f;
  float tv0 = -3.4e38f, tv1 = -3.4e38f, tv2 = -3.4e38f, tv3 = -3.4e38f, tv4 = -3.4e38f;
  int ti0 = 0x7fffffff, ti1 = 0x7fffffff, ti2 = 0x7fffffff, ti3 = 0x7fffffff, ti4 = 0x7fffffff;

  for (int blk = tid; blk < NVBLK; blk += 256) {
    long o = (long)blk * 160 + row;
    float bm = pms[o * 2 + 0], bs = pms[o * 2 + 1];
    float nm = fmaxf(m, bm);
    s = s * expf(m - nm) + bs * expf(bm - nm);
    m = nm;
    float xv; int xi;
    xv = pv[o * 5 + 0]; xi = pi[o * 5 + 0]; INS5(xv, xi);
    xv = pv[o * 5 + 1]; xi = pi[o * 5 + 1]; INS5(xv, xi);
    xv = pv[o * 5 + 2]; xi = pi[o * 5 + 2]; INS5(xv, xi);
    xv = pv[o * 5 + 3]; xi = pi[o * 5 + 3]; INS5(xv, xi);
    xv = pv[o * 5 + 4]; xi = pi[o * 5 + 4]; INS5(xv, xi);
  }
  for (int mask = 1; mask < 64; mask <<= 1) {
    float om = __shfl_xor(m, mask, 64);
    float os = __shfl_xor(s, mask, 64);
    float nm = fmaxf(m, om);
    s = s * expf(m - nm) + os * expf(om - nm);
    m = nm;
  }
  __shared__ float sm[4], ss[4];
  __shared__ float sv[256 * 5];
  __shared__ int   si[256 * 5];
  if ((tid & 63) == 0) { sm[tid >> 6] = m; ss[tid >> 6] = s; }
  sv[tid * 5 + 0] = tv0; si[tid * 5 + 0] = ti0;
  sv[tid * 5 + 1] = tv1; si[tid * 5 + 1] = ti1;
  sv[tid * 5 + 2] = tv2; si[tid * 5 + 2] = ti2;
  sv[tid * 5 + 3] = tv3; si[tid * 5 + 3] = ti3;
  sv[tid * 5 + 4] = tv4; si[tid * 5 + 4] = ti4;
  __syncthreads();
  if (tid == 0) {
    float M2 = sm[0], S2 = ss[0];
    for (int w = 1; w < 4; w++) {
      float nm = fmaxf(M2, sm[w]);
      S2 = S2 * expf(M2 - nm) + ss[w] * expf(sm[w] - nm);
      M2 = nm;
    }
    lse[row] = M2 + logf(S2);
  }
  for (int str = 128; str >= 1; str >>= 1) {
    if (tid < str) {
      float* av = &sv[tid * 5];         int* ai = &si[tid * 5];
      float* bv = &sv[(tid + str) * 5]; int* bi = &si[(tid + str) * 5];
      float o0[5]; int o1[5];
      int i = 0, j = 0;
      #pragma unroll
      for (int o = 0; o < 5; o++) {
        float avv = av[i]; int aii = ai[i];
        float bvv = bv[j]; int bii = bi[j];
        bool ta = cand_gt(avv, aii, bvv, bii);
        o0[o] = ta ? avv : bvv; o1[o] = ta ? aii : bii;
        i += ta ? 1 : 0; j += ta ? 0 : 1;
      }
      #pragma unroll
      for (int o = 0; o < 5; o++) { av[o] = o0[o]; ai[o] = o1[o]; }
    }
    __syncthreads();
  }
  if (tid == 0) {
    #pragma unroll
    for (int o = 0; o < 5; o++) { rv5[row * 5 + o] = sv[o]; ri5[row * 5 + o] = si[o]; }
  }
}

// ---------------- step-0 bookkeeping (row b*KBM only, a = 0) -----------
__global__ void book0_kernel(const float* __restrict__ rv5, const int* __restrict__ ri5,
                             const float* __restrict__ lse,
                             int* __restrict__ seqs, float* __restrict__ act_ll,
                             int* __restrict__ word_buf, int* __restrict__ hsrc,
                             float* __restrict__ best_ll, int* __restrict__ best_seq)
{
  int b = blockIdx.x, tid = threadIdx.x;
  int row = b * KBM;
  float l = lse[row];
  if (tid < SEQL) {
    for (int j = 0; j < KBM; j++) {
      int w = ri5[row * 5 + j];
      seqs[(b * KBM + j) * SEQL + tid] = (tid == 0) ? 0 : (tid == 1 ? w : 2);
    }
    best_seq[b * SEQL + tid] = 2;
  }
  if (tid < KBM) {
    act_ll[b * KBM + tid] = rv5[row * 5 + tid] - l;
    word_buf[b * KBM + tid] = ri5[row * 5 + tid];
    hsrc[b * KBM + tid] = b * KBM + tid;
  }
  if (tid == 0) best_ll[b] = NEGF;
}

// ---------------- per-step bookkeeping (25-candidate merge folded in) ------------
__global__ void book_kernel(const float* __restrict__ rv5, const int* __restrict__ ri5,
                            const float* __restrict__ lse,
                            const int* __restrict__ seqs_old, int* __restrict__ seqs_new,
                            float* __restrict__ act_ll, int* __restrict__ word_buf,
                            int* __restrict__ hsrc, float* __restrict__ best_ll,
                            int* __restrict__ best_seq, int t)
{
  int b = blockIdx.x, tid = threadIdx.x;
  __shared__ float sv5[5];
  __shared__ int   si5[5];
  if (tid == 0) {
    float tv0 = -3.4e38f, tv1 = -3.4e38f, tv2 = -3.4e38f, tv3 = -3.4e38f, tv4 = -3.4e38f;
    int ti0 = 0x7fffffff, ti1 = 0x7fffffff, ti2 = 0x7fffffff, ti3 = 0x7fffffff, ti4 = 0x7fffffff;
    for (int k = 0; k < KBM; k++) {
      int row = b * KBM + k;
      float a = act_ll[row], l = lse[row];
      #pragma unroll
      for (int j = 0; j < 5; j++) {
        float x = a + (rv5[row * 5 + j] - l);
        int id = k * VSZ + ri5[row * 5 + j];
        INS5(x, id);
      }
    }
    sv5[0] = tv0; si5[0] = ti0; sv5[1] = tv1; si5[1] = ti1;
    sv5[2] = tv2; si5[2] = ti2; sv5[3] = tv3; si5[3] = ti3;
    sv5[4] = tv4; si5[4] = ti4;
  }
  __syncthreads();

  __shared__ int ls[KBM][SEQL];
  float v[KBM]; int pr[KBM], wd[KBM];
  #pragma unroll
  for (int j = 0; j < KBM; j++) {
    v[j] = sv5[j];
    int id = si5[j];
    pr[j] = id / VSZ; wd[j] = id % VSZ;
  }
  #pragma unroll
  for (int j = 0; j < KBM; j++) {
    if (tid < SEQL) {
      int x = (tid == t + 1) ? wd[j] : seqs_old[(b * KBM + pr[j]) * SEQL + tid];
      ls[j][tid] = x;
      seqs_new[(b * KBM + j) * SEQL + tid] = x;
    }
  }
  __syncthreads();
  float cll[KBM];
  #pragma unroll
  for (int j = 0; j < KBM; j++) {
    bool fin = v[j] > FINTH;
    bool eos = (wd[j] == 1) && fin;
    cll[j] = eos ? v[j] / (float)(t + 2) : NEGF;
  }
  int jb = 0; float cb = cll[0];
  #pragma unroll
  for (int j = 1; j < KBM; j++) if (cll[j] > cb) { cb = cll[j]; jb = j; }
  bool improve = cb > best_ll[b];
  if (improve) {
    if (tid == 0) best_ll[b] = cb;
    if (tid < SEQL) best_seq[b * SEQL + tid] = ls[jb][tid];
  }
  if (tid < KBM) {
    int j = tid;
    bool fin = v[j] > FINTH;
    bool eos = (wd[j] == 1) && fin;
    act_ll[b * KBM + j] = (fin && !eos) ? v[j] : NEGF;
    word_buf[b * KBM + j] = wd[j];
    hsrc[b * KBM + j] = b * KBM + pr[j];
  }
}

// ---------------- winner selection ----------------
__global__ void final_kernel(const float* __restrict__ best_ll, const int* __restrict__ best_seq,
                             const float* __restrict__ act_ll, const int* __restrict__ seqs,
                             int* __restrict__ out)
{
  int b = blockIdx.x, tid = threadIdx.x;
  bool have = best_ll[b] > FINTH;
  int jb = 0; float ab = act_ll[b * KBM];
  for (int j = 1; j < KBM; j++)
    if (act_ll[b * KBM + j] > ab) { ab = act_ll[b * KBM + j]; jb = j; }
  if (tid < SEQL)
    out[b * SEQL + tid] = have ? best_seq[b * SEQL + tid]
                               : seqs[(b * KBM + jb) * SEQL + tid];
}

extern "C" void kernel_launch(void* const* d_in, const int* in_sizes, int n_in,
                              void* d_out, int out_size, void* d_ws, size_t ws_size,
                              hipStream_t stream)
{
  const int*   source  = (const int*)d_in[0];
  const float* emb_src = (const float*)d_in[1];
  const float* emb_tgt = (const float*)d_in[2];
  const float* eWih = (const float*)d_in[3];
  const float* eWhh = (const float*)d_in[4];
  const float* ebih = (const float*)d_in[5];
  const float* ebhh = (const float*)d_in[6];
  const float* dWih = (const float*)d_in[7];
  const float* dWhh = (const float*)d_in[8];
  const float* dbih = (const float*)d_in[9];
  const float* dbhh = (const float*)d_in[10];
  const float* Wout = (const float*)d_in[11];
  const float* bout = (const float*)d_in[12];
  int* out = (int*)d_out;

  char* ws = (char*)d_ws;
  size_t off = 0;
  auto alloc = [&](size_t bytes) {
    void* p = ws + off;
    off = (off + bytes + 255) & ~(size_t)255;
    return p;
  };
  float* hb0     = (float*)alloc(160 * 512 * 4);
  float* hb1     = (float*)alloc(160 * 512 * 4);
  float* gip     = (float*)alloc((size_t)4 * 160 * 1536 * 4);
  float* ghp     = (float*)alloc((size_t)4 * 160 * 1536 * 4);
  char*  uni     = (char*) alloc((size_t)8 * 1024 * 1024);   // gi_enc aliases partials
  float* gi_enc  = (float*)uni;                              // 1024*1536*4 = 6.29 MB
  float* pms     = (float*)uni;                              // 1000*160*2*4 = 1.28 MB
  float* pv      = (float*)(uni + 1536 * 1024);              // 1000*160*5*4 = 3.20 MB
  int*   pi      = (int*)  (uni + 1536 * 1024 + 3328 * 1024);
  float* lse     = (float*)alloc(160 * 4);
  float* act_ll  = (float*)alloc(160 * 4);
  float* rv5     = (float*)alloc(160 * 5 * 4);
  float* best_ll = (float*)alloc(32 * 4);
  int*   ri5     = (int*)alloc(160 * 5 * 4);
  int*   seqs0   = (int*)alloc(160 * SEQL * 4);
  int*   seqs1   = (int*)alloc(160 * SEQL * 4);
  int*   wordb   = (int*)alloc(160 * 4);
  int*   hsrc    = (int*)alloc(160 * 4);
  int*   bseq    = (int*)alloc(32 * SEQL * 4);

  init_kernel<<<64, 256, 0, stream>>>(hb0, wordb, hsrc);

  // ---- encoder: batched gi for all 32 steps, then serial gh + update ----
  genc_kernel<<<dim3(96, 8), 256, 0, stream>>>(emb_src, source, eWih, gi_enc);
  for (int s = 0; s < 32; s++) {
    gates_kernel<1, 1><<<dim3(96, 1, 4), 256, 0, stream>>>(
        nullptr, nullptr, 0, hb0, nullptr, nullptr, eWhh, nullptr, ghp);
    hupd_kernel<1, 4, 32><<<64, 256, 0, stream>>>(
        gi_enc + (size_t)s * 32 * 1536, ghp, ebih, ebhh, hb0, nullptr, hb0);
  }

  // ---- decode step 0 (initial advance) ----
  gates_kernel<5, 0><<<dim3(96, 2, 4), 256, 0, stream>>>(
      emb_tgt, wordb, 1, hb0, hsrc, dWih, dWhh, gip, ghp);
  hupd_kernel<4, 4, 160><<<320, 256, 0, stream>>>(
      gip, ghp, dbih, dbhh, hb0, hsrc, hb1);
  logtop_kernel<<<NVBLK, 256, 0, stream>>>(hb1, Wout, bout, pms, pv, pi);
  merge_kernel<<<160, 256, 0, stream>>>(pms, pv, pi, lse, rv5, ri5);
  book0_kernel<<<32, 64, 0, stream>>>(rv5, ri5, lse, seqs0, act_ll, wordb, hsrc,
                                      best_ll, bseq);

  // ---- decode steps t = 1..32 ----
  float* hcur = hb1; float* hoth = hb0;
  int* scur = seqs0; int* soth = seqs1;
  for (int t = 1; t <= 32; t++) {
    gates_kernel<5, 0><<<dim3(96, 2, 4), 256, 0, stream>>>(
        emb_tgt, wordb, 1, hcur, hsrc, dWih, dWhh, gip, ghp);
    hupd_kernel<4, 4, 160><<<320, 256, 0, stream>>>(
        gip, ghp, dbih, dbhh, hcur, hsrc, hoth);
    logtop_kernel<<<NVBLK, 256, 0, stream>>>(hoth, Wout, bout, pms, pv, pi);
    merge_kernel<<<160, 256, 0, stream>>>(pms, pv, pi, lse, rv5, ri5);
    book_kernel<<<32, 64, 0, stream>>>(rv5, ri5, lse, scur, soth, act_ll, wordb,
                                       hsrc, best_ll, bseq, t);
    { float* tmp = hcur; hcur = hoth; hoth = tmp; }
    { int* tmp = scur; scur = soth; soth = tmp; }
  }

  final_kernel<<<32, 64, 0, stream>>>(best_ll, bseq, act_ll, scur, out);
}